// Round 6
// baseline (969.018 us; speedup 1.0000x reference)
//
#include <hip/hip_runtime.h>
#include <cmath>

typedef unsigned short u16;
typedef __attribute__((ext_vector_type(8))) short short8;
typedef __attribute__((ext_vector_type(4))) float f32x4;
typedef __attribute__((ext_vector_type(4))) u16 u16x4;

// ---------- bf16 helpers ----------
__device__ __forceinline__ float b2f(u16 u) {
    unsigned x = ((unsigned)u) << 16;
    return __builtin_bit_cast(float, x);
}
__device__ __forceinline__ u16 f2b(float f) {
    unsigned x = __builtin_bit_cast(unsigned, f);
    unsigned r = (x + 0x7fffu + ((x >> 16) & 1u)) >> 16;   // RNE
    return (u16)r;
}
__device__ __forceinline__ float loadx(const void* p, size_t i, int f32) {
    return f32 ? ((const float*)p)[i] : b2f(((const u16*)p)[i]);
}
// load 8 consecutive elements as bf16 short8 from raw tensor (bf16 fast path)
__device__ __forceinline__ short8 ldb8(const void* p, size_t e, int f32) {
    if (!f32) return *(const short8*)((const u16*)p + e);
    const float* fp = (const float*)p + e;
    f32x4 a = *(const f32x4*)fp, b = *(const f32x4*)(fp + 4);
    short8 r;
    r[0] = (short)f2b(a[0]); r[1] = (short)f2b(a[1]);
    r[2] = (short)f2b(a[2]); r[3] = (short)f2b(a[3]);
    r[4] = (short)f2b(b[0]); r[5] = (short)f2b(b[1]);
    r[6] = (short)f2b(b[2]); r[7] = (short)f2b(b[3]);
    return r;
}
// load 4 consecutive elements as fp32
__device__ __forceinline__ f32x4 ld4f(const void* p, size_t e, int f32) {
    f32x4 r;
    if (f32) { r = *(const f32x4*)((const float*)p + e); }
    else {
        u16x4 t = *(const u16x4*)((const u16*)p + e);
        r[0] = b2f(t[0]); r[1] = b2f(t[1]); r[2] = b2f(t[2]); r[3] = b2f(t[3]);
    }
    return r;
}
// stage 8 elements (bf16) into LDS from fp32 src (fallback path)
__device__ __forceinline__ void stage8f(u16* dst, const void* src, size_t eoff) {
    const f32x4* s = (const f32x4*)((const float*)src + eoff);
    f32x4 a = s[0], b = s[1];
    uint4 p;
    p.x = (unsigned)f2b(a[0]) | ((unsigned)f2b(a[1]) << 16);
    p.y = (unsigned)f2b(a[2]) | ((unsigned)f2b(a[3]) << 16);
    p.z = (unsigned)f2b(b[0]) | ((unsigned)f2b(b[1]) << 16);
    p.w = (unsigned)f2b(b[2]) | ((unsigned)f2b(b[3]) << 16);
    *(uint4*)dst = p;
}
// async global->LDS, 16B/lane; LDS dest = wave-uniform base + lane*16
__device__ __forceinline__ void gl_lds16(const void* g, void* l) {
    __builtin_amdgcn_global_load_lds(
        (const __attribute__((address_space(1))) void*)g,
        (__attribute__((address_space(3))) void*)l, 16, 0, 0);
}
// fast gelu (tanh form; |err| ~3e-3 absolute — noise after 0.02-scale fc2)
__device__ __forceinline__ float gelu_f(float x) {
    float y = 0.7978845608028654f * (x + 0.044715f * x * x * x);
    float e = __expf(2.f * y);
    float t = 1.f - 2.f / (e + 1.f);    // tanh(y)
    return 0.5f * x * (1.f + t);
}

// ---------- problem constants ----------
#define BB 8
#define NN 4096
#define CC 256
#define HH 8
#define DD 32
#define HID 1024
#define MTOK (BB*NN)
#define TOKEL ((size_t)MTOK*CC)

// ws offsets (bytes) — total 112 MiB + 4 B
#define WS_INPUT_POS 0u
#define WS_PHIQ   16777216u
#define WS_PHIK   33554432u      /* phik_t -> attn_proj */
#define WS_V      50331648u
#define WS_XLN    67108864u      /* x_ln -> attn_tok */
#define WS_SLN    83886080u      /* s_ln -> kv fp32 */
#define WS_OUTPRE 100663296u
#define WS_FLAG   117440512u

// =====================================================================
// K0: dtype detect
// =====================================================================
__global__ __launch_bounds__(64) void detect_kernel(const u16* __restrict__ in0,
                                                    int* __restrict__ flag)
{
    int t = threadIdx.x;
    u16 w = in0[2 * t];
    int e = (w >> 7) & 0xFF;
    int bad = (e < 64 || e > 192) ? 1 : 0;
    unsigned long long m = __ballot(bad);
    if (t == 0) *flag = (__popcll(m) > 8) ? 1 : 0;
}

// =====================================================================
// K1: input_pos = input_+pos ; x_ln = LN1(input_pos) ; s_ln = LN2(prev)
// =====================================================================
__global__ __launch_bounds__(256) void prep_kernel(
    const void* __restrict__ inp, const void* __restrict__ prev,
    const void* __restrict__ pos,
    const void* __restrict__ w1, const void* __restrict__ b1,
    const void* __restrict__ w2, const void* __restrict__ b2,
    u16* __restrict__ input_pos, u16* __restrict__ x_ln, u16* __restrict__ s_ln,
    const int* __restrict__ flagp)
{
    const int f32 = *flagp;
    const int m = blockIdx.x;
    const int c = threadIdx.x;
    const int n = m & (NN - 1);
    const size_t idx = (size_t)m * CC + c;

    __shared__ float red[8];

    float ip = loadx(inp, idx, f32) + loadx(pos, (size_t)n * CC + c, f32);
    float s = ip, s2 = ip * ip;
    #pragma unroll
    for (int o = 32; o; o >>= 1) { s += __shfl_down(s, o, 64); s2 += __shfl_down(s2, o, 64); }
    if ((threadIdx.x & 63) == 0) { int w6 = threadIdx.x >> 6; red[w6] = s; red[4 + w6] = s2; }
    __syncthreads();
    float mu  = (red[0] + red[1] + red[2] + red[3]) * (1.f / 256.f);
    float var = (red[4] + red[5] + red[6] + red[7]) * (1.f / 256.f) - mu * mu;
    float rs = rsqrtf(var + 1e-5f);
    input_pos[idx] = f2b(ip);
    x_ln[idx] = f2b((ip - mu) * rs * loadx(w1, c, f32) + loadx(b1, c, f32));
    __syncthreads();

    float pv = loadx(prev, idx, f32);
    s = pv; s2 = pv * pv;
    #pragma unroll
    for (int o = 32; o; o >>= 1) { s += __shfl_down(s, o, 64); s2 += __shfl_down(s2, o, 64); }
    if ((threadIdx.x & 63) == 0) { int w6 = threadIdx.x >> 6; red[w6] = s; red[4 + w6] = s2; }
    __syncthreads();
    mu  = (red[0] + red[1] + red[2] + red[3]) * (1.f / 256.f);
    var = (red[4] + red[5] + red[6] + red[7]) * (1.f / 256.f) - mu * mu;
    rs = rsqrtf(var + 1e-5f);
    s_ln[idx] = f2b((pv - mu) * rs * loadx(w2, c, f32) + loadx(b2, c, f32));
}

// =====================================================================
// K3: kv[bh][d][e] = sum_n phik_t[bh][d][n] * v_t[bh][e][n]  (MFMA split-K)
// =====================================================================
__global__ __launch_bounds__(64) void kv_mfma(
    const u16* __restrict__ phik_t, const u16* __restrict__ v_t,
    float* __restrict__ kvout)
{
    const int bh = blockIdx.x;
    const int k0 = blockIdx.y * 256;
    const int lane = threadIdx.x;
    const int quad = lane >> 4, lr = lane & 15;

    const u16* A = phik_t + (size_t)bh * DD * NN;
    const u16* W = v_t    + (size_t)bh * DD * NN;

    f32x4 acc[2][2];
    #pragma unroll
    for (int i = 0; i < 2; ++i)
        #pragma unroll
        for (int j = 0; j < 2; ++j) { f32x4 z = {0.f,0.f,0.f,0.f}; acc[i][j] = z; }

    for (int kk = k0; kk < k0 + 256; kk += 32) {
        short8 a0 = *(const short8*)(A + (size_t)lr * NN + kk + quad * 8);
        short8 a1 = *(const short8*)(A + (size_t)(16 + lr) * NN + kk + quad * 8);
        short8 w0 = *(const short8*)(W + (size_t)lr * NN + kk + quad * 8);
        short8 w1 = *(const short8*)(W + (size_t)(16 + lr) * NN + kk + quad * 8);
        acc[0][0] = __builtin_amdgcn_mfma_f32_16x16x32_bf16(a0, w0, acc[0][0], 0, 0, 0);
        acc[0][1] = __builtin_amdgcn_mfma_f32_16x16x32_bf16(a0, w1, acc[0][1], 0, 0, 0);
        acc[1][0] = __builtin_amdgcn_mfma_f32_16x16x32_bf16(a1, w0, acc[1][0], 0, 0, 0);
        acc[1][1] = __builtin_amdgcn_mfma_f32_16x16x32_bf16(a1, w1, acc[1][1], 0, 0, 0);
    }
    float* base = kvout + (size_t)bh * (DD * DD);
    #pragma unroll
    for (int i = 0; i < 2; ++i)
        #pragma unroll
        for (int j = 0; j < 2; ++j)
            #pragma unroll
            for (int r = 0; r < 4; ++r)
                atomicAdd(base + (i * 16 + quad * 4 + r) * DD + j * 16 + lr, acc[i][j][r]);
}

// =====================================================================
// K4: attn_tok = phiq @ kv  (MFMA, no LDS)
// =====================================================================
__global__ __launch_bounds__(256) void attn_mfma(
    const u16* __restrict__ phiq, const float* __restrict__ kv,
    u16* __restrict__ attn_tok)
{
    const int bh = blockIdx.x;
    const int b = bh >> 3, h = bh & 7;
    const int wv = threadIdx.x >> 6, lane = threadIdx.x & 63;
    const int quad = lane >> 4, lr = lane & 15;

    const float* kvb = kv + (size_t)bh * (DD * DD);
    short8 bf0, bf1;
    #pragma unroll
    for (int j = 0; j < 8; ++j) {
        int d = quad * 8 + j;
        bf0[j] = (short)f2b(kvb[d * DD + lr]);
        bf1[j] = (short)f2b(kvb[d * DD + 16 + lr]);
    }

    const u16* qb = phiq + (size_t)bh * NN * DD;
    const int n0 = blockIdx.y * 512 + wv * 128;
    #pragma unroll
    for (int t = 0; t < 8; ++t) {
        const int nt = n0 + t * 16;
        short8 af = *(const short8*)(qb + (size_t)(nt + lr) * DD + quad * 8);
        f32x4 c0 = {0.f,0.f,0.f,0.f}, c1 = {0.f,0.f,0.f,0.f};
        c0 = __builtin_amdgcn_mfma_f32_16x16x32_bf16(af, bf0, c0, 0, 0, 0);
        c1 = __builtin_amdgcn_mfma_f32_16x16x32_bf16(af, bf1, c1, 0, 0, 0);
        size_t base = ((size_t)b * NN + nt + quad * 4) * CC + h * DD;
        #pragma unroll
        for (int r = 0; r < 4; ++r) {
            attn_tok[base + (size_t)r * CC + lr]      = f2b(c0[r]);
            attn_tok[base + (size_t)r * CC + 16 + lr] = f2b(c1[r]);
        }
    }
}

// =====================================================================
// MFMA GEMM (qkv/proj/gate): XCD-swizzled 128x128 tile, BK=32
// MODE: 0=QKV 1=PROJ 2=GATE
// =====================================================================
#define BM 128
#define BN 128
#define BK 32
#define LDT 32

template <int MODE, int RAWA>
__global__ __launch_bounds__(256) void gemm_bt(
    const void* __restrict__ A1, const void* __restrict__ A2,
    const void* __restrict__ W1, const void* __restrict__ W2,
    int lda, int ldw, int K, int Ksplit, int wcol2,
    const void* __restrict__ bias,
    u16* __restrict__ o0, u16* __restrict__ o1,
    const u16* __restrict__ xa, const void* __restrict__ xr,
    void* __restrict__ oraw, const int* __restrict__ flagp)
{
    __shared__ u16 ash[BM * LDT];
    __shared__ u16 bsh[BN * LDT];

    const int f32 = *flagp;
    const int af32 = RAWA ? f32 : 0;

    // XCD-aware swizzle: all x-blocks of a y-band land on one XCD (L2 A-reuse)
    const int gx = gridDim.x, gy8 = gridDim.y >> 3;
    int id = blockIdx.y * gx + blockIdx.x;
    int xcd = id & 7, slot = id >> 3;
    const int bx = slot % gx;
    const int by = xcd * gy8 + slot / gx;

    const int tid = threadIdx.x;
    const int lane = tid & 63;
    const int wv = tid >> 6;
    const int wm = wv >> 1, wn = wv & 1;
    const int quad = lane >> 4, lr = lane & 15;

    const bool swp = (MODE == 0) ? (bx < 2) : true;

    f32x4 acc[4][4];
    #pragma unroll
    for (int i = 0; i < 4; ++i)
        #pragma unroll
        for (int j = 0; j < 4; ++j) { f32x4 z = {0.f,0.f,0.f,0.f}; acc[i][j] = z; }

    const size_t arow0 = (size_t)by * BM;
    const size_t wrow0 = (size_t)bx * BN;

    const int srow = lane >> 2;
    const int skc  = (lane & 3) << 3;

    for (int k0 = 0; k0 < K; k0 += BK) {
        const void* As; const void* Ws; int ka, kw;
        if (k0 < Ksplit) { As = A1; Ws = W1; ka = k0;          kw = k0; }
        else             { As = A2; Ws = W2; ka = k0 - Ksplit; kw = k0 - Ksplit + wcol2; }

        if (!af32) {
            const u16* ga = (const u16*)As + (arow0 + wv * 32 + srow) * (size_t)lda + ka + skc;
            u16* la = ash + (wv * 32) * LDT;
            gl_lds16(ga, la);
            gl_lds16(ga + (size_t)16 * lda, la + 16 * LDT);
        } else {
            #pragma unroll
            for (int half = 0; half < 2; ++half) {
                int row = wv * 32 + half * 16 + srow;
                stage8f(ash + row * LDT + skc, As, (arow0 + row) * (size_t)lda + ka + skc);
            }
        }
        if (!f32) {
            const u16* gw = (const u16*)Ws + (wrow0 + wv * 32 + srow) * (size_t)ldw + kw + skc;
            u16* lb = bsh + (wv * 32) * LDT;
            gl_lds16(gw, lb);
            gl_lds16(gw + (size_t)16 * ldw, lb + 16 * LDT);
        } else {
            #pragma unroll
            for (int half = 0; half < 2; ++half) {
                int row = wv * 32 + half * 16 + srow;
                stage8f(bsh + row * LDT + skc, Ws, (wrow0 + row) * (size_t)ldw + kw + skc);
            }
        }
        __syncthreads();

        short8 af[4], bf[4];
        #pragma unroll
        for (int i = 0; i < 4; ++i)
            af[i] = *(const short8*)(ash + (wm * 64 + i * 16 + lr) * LDT + quad * 8);
        #pragma unroll
        for (int j = 0; j < 4; ++j)
            bf[j] = *(const short8*)(bsh + (wn * 64 + j * 16 + lr) * LDT + quad * 8);
        if (swp) {
            #pragma unroll
            for (int i = 0; i < 4; ++i)
                #pragma unroll
                for (int j = 0; j < 4; ++j)
                    acc[i][j] = __builtin_amdgcn_mfma_f32_16x16x32_bf16(bf[j], af[i], acc[i][j], 0, 0, 0);
        } else {
            #pragma unroll
            for (int i = 0; i < 4; ++i)
                #pragma unroll
                for (int j = 0; j < 4; ++j)
                    acc[i][j] = __builtin_amdgcn_mfma_f32_16x16x32_bf16(af[i], bf[j], acc[i][j], 0, 0, 0);
        }
        __syncthreads();
    }

    const int mbase = by * BM + wm * 64;
    const int nbase = bx * BN + wn * 64;

    #pragma unroll
    for (int i = 0; i < 4; ++i) {
        #pragma unroll
        for (int j = 0; j < 4; ++j) {
            if (MODE == 0) {
                if (swp) {
                    const int m = mbase + i * 16 + lr;
                    const int b = m >> 12, n = m & (NN - 1);
                    const int c0 = nbase + j * 16 + quad * 4;
                    const int h = c0 >> 5, d0 = c0 & 31;
                    u16x4 p;
                    #pragma unroll
                    for (int r = 0; r < 4; ++r) {
                        float v = acc[i][j][r];
                        p[r] = f2b((v > 0.f) ? (v + 1.f) : __expf(v));
                    }
                    *(u16x4*)(o0 + (((size_t)b * HH + h) * NN + n) * DD + d0) = p;
                } else {
                    const int c = nbase + j * 16 + lr;
                    const int which = c >> 8, rem = c & 255, h = rem >> 5, d = rem & 31;
                    const int m0 = mbase + i * 16 + quad * 4;
                    const int b = m0 >> 12, n0i = m0 & (NN - 1);
                    u16x4 p;
                    #pragma unroll
                    for (int r = 0; r < 4; ++r) {
                        float v = acc[i][j][r];
                        if (which == 1) v = (v > 0.f) ? (v + 1.f) : __expf(v);
                        p[r] = f2b(v);
                    }
                    u16* dst = o0 + (size_t)which * TOKEL;
                    *(u16x4*)(dst + (((size_t)b * HH + h) * DD + d) * NN + n0i) = p;
                }
            } else {
                const int m = mbase + i * 16 + lr;
                const int c0 = nbase + j * 16 + quad * 4;
                const size_t idx0 = (size_t)m * CC + c0;
                f32x4 bias4 = ld4f(bias, c0, f32);
                if (MODE == 1) {
                    u16x4 xa4 = *(const u16x4*)(xa + idx0);
                    u16x4 po, pr;
                    #pragma unroll
                    for (int r = 0; r < 4; ++r) {
                        float val = acc[i][j][r] + bias4[r];
                        po[r] = f2b(val);
                        pr[r] = f2b(b2f(xa4[r]) + val);
                    }
                    *(u16x4*)(o0 + idx0) = po;
                    *(u16x4*)(o1 + idx0) = pr;
                } else {  // MODE 2: gate
                    u16x4 ap4 = *(const u16x4*)(xa + idx0);
                    if (f32) {
                        f32x4 pv = *(const f32x4*)((const float*)xr + idx0);
                        f32x4 o;
                        #pragma unroll
                        for (int r = 0; r < 4; ++r) {
                            float u = 1.f / (1.f + __expf(-(acc[i][j][r] + bias4[r])));
                            o[r] = pv[r] * (1.f - u) + b2f(ap4[r]) * u;
                        }
                        *(f32x4*)((float*)oraw + TOKEL + idx0) = o;
                    } else {
                        u16x4 pv = *(const u16x4*)((const u16*)xr + idx0);
                        u16x4 o;
                        #pragma unroll
                        for (int r = 0; r < 4; ++r) {
                            float u = 1.f / (1.f + __expf(-(acc[i][j][r] + bias4[r])));
                            o[r] = f2b(b2f(pv[r]) * (1.f - u) + b2f(ap4[r]) * u);
                        }
                        *(u16x4*)((u16*)oraw + TOKEL + idx0) = o;
                    }
                }
            }
        }
    }
}

// =====================================================================
// Fused MLP: out = outpre + fc2(gelu(fc1(LN3(outpre)))), barrier-light.
// Block = 64 tokens, 4 waves; wave owns 16 tokens end-to-end.
// A (normalized) in padded LDS (wave-private rows); B-frags straight
// from global (weights are L2-resident); h round-trips wave-private LDS.
// =====================================================================
#define MBM 64
__global__ __launch_bounds__(256, 2) void mlp_kernel(
    const u16* __restrict__ outpre,
    const void* __restrict__ w3, const void* __restrict__ b3,
    const void* __restrict__ fc1w, const void* __restrict__ fc1b,
    const void* __restrict__ fc2w, const void* __restrict__ fc2b,
    void* __restrict__ dout, const int* __restrict__ flagp)
{
    const int f32 = *flagp;
    __shared__ u16 alds[8 * MBM * 40];   // [kt][row][40] padded, 40 KB
    __shared__ u16 hlds[4 * 16 * 136];   // per-wave [16][136] padded, 17 KB

    const int tid = threadIdx.x;
    const int wv = tid >> 6, lane = tid & 63;
    const int quad = lane >> 4, lr = lane & 15;
    const int row0 = blockIdx.x * MBM;

    // ---- LN3: lane handles row r4 = wv*16 + (lane>>2), cols sub*8 + kt*32
    {
        const int r4 = wv * 16 + (lane >> 2);
        const int sub = lane & 3;
        const u16* src = outpre + (size_t)(row0 + r4) * CC + sub * 8;
        short8 xv[8];
        #pragma unroll
        for (int kt = 0; kt < 8; ++kt)
            xv[kt] = *(const short8*)(src + kt * 32);
        float s = 0.f, s2 = 0.f;
        #pragma unroll
        for (int kt = 0; kt < 8; ++kt)
            #pragma unroll
            for (int j = 0; j < 8; ++j) {
                float x = b2f((u16)xv[kt][j]); s += x; s2 += x * x;
            }
        s += __shfl_xor(s, 1, 64);  s2 += __shfl_xor(s2, 1, 64);
        s += __shfl_xor(s, 2, 64);  s2 += __shfl_xor(s2, 2, 64);
        float mu = s * (1.f / 256.f);
        float var = s2 * (1.f / 256.f) - mu * mu;
        float rs = rsqrtf(var + 1e-5f);
        #pragma unroll
        for (int kt = 0; kt < 8; ++kt) {
            int cb = kt * 32 + sub * 8;
            short8 wv8 = ldb8(w3, cb, f32);
            short8 bv8 = ldb8(b3, cb, f32);
            short8 o;
            #pragma unroll
            for (int j = 0; j < 8; ++j) {
                float xh = (b2f((u16)xv[kt][j]) - mu) * rs;
                o[j] = (short)f2b(xh * b2f((u16)wv8[j]) + b2f((u16)bv8[j]));
            }
            *(short8*)(alds + kt * (MBM * 40) + r4 * 40 + sub * 8) = o;
        }
    }
    __syncthreads();   // safety fence for LDS ordering

    u16* hbuf = hlds + wv * (16 * 136);
    f32x4 oacc[16];
    #pragma unroll
    for (int j = 0; j < 16; ++j) { f32x4 z = {0.f,0.f,0.f,0.f}; oacc[j] = z; }

    for (int hc = 0; hc < 8; ++hc) {
        // GEMM1: h[16 tok,128] = A[16,256] @ fc1w[hc-slice]^T (swapped MFMA)
        f32x4 hacc[8];
        #pragma unroll
        for (int j = 0; j < 8; ++j) { f32x4 z = {0.f,0.f,0.f,0.f}; hacc[j] = z; }
        #pragma unroll
        for (int kt = 0; kt < 8; ++kt) {
            short8 af = *(const short8*)(alds + kt * (MBM * 40) + (wv * 16 + lr) * 40 + quad * 8);
            #pragma unroll
            for (int j = 0; j < 8; ++j) {
                short8 bf = ldb8(fc1w, (size_t)(hc * 128 + j * 16 + lr) * CC + kt * 32 + quad * 8, f32);
                hacc[j] = __builtin_amdgcn_mfma_f32_16x16x32_bf16(bf, af, hacc[j], 0, 0, 0);
            }
        }
        // bias + gelu -> wave-private LDS (token=lr, col=j*16+quad*4+r)
        #pragma unroll
        for (int j = 0; j < 8; ++j) {
            f32x4 bb = ld4f(fc1b, hc * 128 + j * 16 + quad * 4, f32);
            u16x4 p;
            #pragma unroll
            for (int r = 0; r < 4; ++r)
                p[r] = f2b(gelu_f(hacc[j][r] + bb[r]));
            *(u16x4*)(hbuf + lr * 136 + j * 16 + quad * 4) = p;
        }
        __syncthreads();   // lgkm fence: h writes visible before A-frag reads

        // GEMM2: oacc += h[16,128] @ fc2w[:, hc-slice]^T (swapped MFMA)
        #pragma unroll
        for (int kt2 = 0; kt2 < 4; ++kt2) {
            short8 af2 = *(const short8*)(hbuf + lr * 136 + kt2 * 32 + quad * 8);
            #pragma unroll
            for (int j2 = 0; j2 < 16; ++j2) {
                short8 bf2 = ldb8(fc2w, (size_t)(j2 * 16 + lr) * HID + hc * 128 + kt2 * 32 + quad * 8, f32);
                oacc[j2] = __builtin_amdgcn_mfma_f32_16x16x32_bf16(bf2, af2, oacc[j2], 0, 0, 0);
            }
        }
        __syncthreads();   // protect hbuf before next hc overwrites
    }

    // epilogue: out = outpre + oacc + fc2b
    const int m = row0 + wv * 16 + lr;
    #pragma unroll
    for (int j2 = 0; j2 < 16; ++j2) {
        const int c0 = j2 * 16 + quad * 4;
        const size_t idx = (size_t)m * CC + c0;
        f32x4 bb = ld4f(fc2b, c0, f32);
        u16x4 xp = *(const u16x4*)(outpre + idx);
        if (f32) {
            f32x4 o;
            #pragma unroll
            for (int r = 0; r < 4; ++r) o[r] = b2f(xp[r]) + oacc[j2][r] + bb[r];
            *(f32x4*)((float*)dout + idx) = o;
        } else {
            u16x4 o;
            #pragma unroll
            for (int r = 0; r < 4; ++r) o[r] = f2b(b2f(xp[r]) + oacc[j2][r] + bb[r]);
            *(u16x4*)((u16*)dout + idx) = o;
        }
    }
}

// =====================================================================
extern "C" void kernel_launch(void* const* d_in, const int* in_sizes, int n_in,
                              void* d_out, int out_size, void* d_ws, size_t ws_size,
                              hipStream_t stream)
{
    const void* input_ = d_in[0];
    const void* prev   = d_in[1];
    const void* pos    = d_in[2];
    const void* n1w = d_in[3];  const void* n1b = d_in[4];
    const void* n2w = d_in[5];  const void* n2b = d_in[6];
    const void* n3w = d_in[7];  const void* n3b = d_in[8];
    const void* qkvi = d_in[9]; const void* qkvs = d_in[10];
    const void* projw = d_in[11]; const void* projb = d_in[12];
    const void* gatew = d_in[13]; const void* gateb = d_in[14];
    const void* fc1w = d_in[15]; const void* fc1b = d_in[16];
    const void* fc2w = d_in[17]; const void* fc2b = d_in[18];

    char* ws = (char*)d_ws;
    u16* input_pos = (u16*)(ws + WS_INPUT_POS);
    u16* phiq  = (u16*)(ws + WS_PHIQ);
    u16* phikt = (u16*)(ws + WS_PHIK);
    u16* vt    = (u16*)(ws + WS_V);
    u16* x_ln = (u16*)(ws + WS_XLN);
    u16* s_ln = (u16*)(ws + WS_SLN);
    u16* attn_tok = x_ln;
    u16* attn_proj = phikt;
    float* kvf = (float*)(ws + WS_SLN);
    u16* outpre = (u16*)(ws + WS_OUTPRE);
    int* flagp = (int*)(ws + WS_FLAG);

    // K0 dtype detect
    detect_kernel<<<1, 64, 0, stream>>>((const u16*)input_, flagp);
    // K1 prep
    prep_kernel<<<MTOK, 256, 0, stream>>>(input_, prev, pos, n1w, n1b, n2w, n2b,
                                          input_pos, x_ln, s_ln, flagp);
    // K2 qkv: phi fused; q->[B,H,N,D], k/v->[B,H,D,N]
    gemm_bt<0, 0><<<dim3(3 * CC / BN, MTOK / BM), 256, 0, stream>>>(
        x_ln, s_ln, qkvi, qkvs, CC, CC, 2 * CC, CC, 0, nullptr,
        phiq, nullptr, nullptr, nullptr, nullptr, flagp);
    // K3 kv einsum
    hipMemsetAsync((void*)kvf, 0, BB * HH * DD * DD * sizeof(float), stream);
    kv_mfma<<<dim3(BB * HH, 16), 64, 0, stream>>>(phikt, vt, kvf);
    // K4 attn tokens
    attn_mfma<<<dim3(BB * HH, NN / 512), 256, 0, stream>>>(phiq, kvf, attn_tok);
    // K5 proj: attn_proj(ws); outpre = input_pos + attn_proj
    gemm_bt<1, 0><<<dim3(CC / BN, MTOK / BM), 256, 0, stream>>>(
        attn_tok, attn_tok, projw, projw, CC, CC, CC, CC, 0, projb,
        attn_proj, outpre, input_pos, nullptr, nullptr, flagp);
    // K6 gate: new_state -> d_out (+TOKEL)
    gemm_bt<2, 1><<<dim3(CC / BN, MTOK / BM), 256, 0, stream>>>(
        input_, prev, gatew, gatew, CC, 2 * CC, 2 * CC, CC, CC, gateb,
        nullptr, nullptr, attn_proj, prev, d_out, flagp);
    // K7 fused MLP (ln3 + fc1 + gelu + fc2 + residual) -> d_out[output]
    mlp_kernel<<<MTOK / MBM, 256, 0, stream>>>(
        outpre, n3w, n3b, fc1w, fc1b, fc2w, fc2b, d_out, flagp);
}